// Round 4
// baseline (552.190 us; speedup 1.0000x reference)
//
#include <hip/hip_runtime.h>
#include <hip/hip_bf16.h>

#define NN 8192
#define FIN 256
#define FOUT 64

typedef __attribute__((ext_vector_type(8))) short short8;
typedef __attribute__((ext_vector_type(4))) float f32x4;
typedef __attribute__((ext_vector_type(4))) int   iv4;

__device__ __forceinline__ unsigned short f2bf(float x){
  unsigned u = __float_as_uint(x);
  u += 0x7FFFu + ((u >> 16) & 1u);      // RTNE
  return (unsigned short)(u >> 16);
}

// ---- k_prep_a: partial Wh = h@W over a k-chunk of 64. lane = row (64 rows/wave),
// W read via uniform (scalar) loads, h staged in LDS with float4 XOR swizzle.
// grid: 32 row-groups x 4 k-splits = 128 blocks x 256 thr.
__global__ __launch_bounds__(256) void k_prep_a(const float* __restrict__ h,
    const float* __restrict__ W, float* __restrict__ pWh){
  __shared__ float hs[256][64];   // 64 KB, [row][k'] with k'-float4 XOR swizzle
  const int t = threadIdx.x;
  const int rowbase = (blockIdx.x & 31) * 256;
  const int ks      = blockIdx.x >> 5;
  const int kbase   = ks * 64;
  // stage h[rowbase..+255][kbase..+63], swizzled: float4 col' = kq ^ (row&15)
  #pragma unroll
  for (int i = 0; i < 16; ++i){
    int idx = i*256 + t;
    int row = idx >> 4, kq = idx & 15;
    float4 v = *(const float4*)(h + (size_t)(rowbase+row)*FIN + kbase + kq*4);
    *(float4*)&hs[row][(kq ^ (row & 15)) * 4] = v;
  }
  __syncthreads();
  const int l = t & 63, wv = t >> 6;
  const int rr = wv*64 + l;             // row within block
  float acc[64];
  #pragma unroll
  for (int f = 0; f < 64; ++f) acc[f] = 0.f;
  #pragma unroll 1
  for (int kq = 0; kq < 16; ++kq){
    float4 hv = *(const float4*)&hs[rr][(kq ^ (rr & 15)) * 4];
    const float hj[4] = {hv.x, hv.y, hv.z, hv.w};
    #pragma unroll
    for (int j = 0; j < 4; ++j){
      const float* wrow = W + (size_t)(kbase + kq*4 + j)*FOUT;   // uniform -> s_load
      #pragma unroll
      for (int f = 0; f < 64; ++f)
        acc[f] = fmaf(hj[j], wrow[f], acc[f]);
    }
  }
  float* op = pWh + (size_t)ks*(NN*FOUT) + (size_t)(rowbase + rr)*FOUT;
  #pragma unroll
  for (int f4 = 0; f4 < 16; ++f4)
    *(float4*)(op + f4*4) = *(float4*)&acc[f4*4];
}

// ---- k_prep_b: Wh = sum of 4 partials; emit WhT (bf16 [64][8192]), fs, fd, gmax.
// grid: 2048 blocks x 256 thr; wave = one row, lane = feature.
__global__ __launch_bounds__(256) void k_prep_b(const float* __restrict__ pWh,
    const float* __restrict__ a, unsigned short* __restrict__ WhT,
    float* __restrict__ fs, float* __restrict__ fd, unsigned* __restrict__ gmax_u){
  const int t = threadIdx.x, l = t & 63, wv = t >> 6;
  const int row = blockIdx.x*4 + wv;
  const size_t off = (size_t)row*FOUT + l;
  float Wh = pWh[off] + pWh[off + NN*FOUT] + pWh[off + 2*NN*FOUT] + pWh[off + 3*NN*FOUT];
  float p = Wh * a[l], q = Wh * a[64 + l];
  #pragma unroll
  for (int m = 1; m < 64; m <<= 1){
    p += __shfl_xor(p, m); q += __shfl_xor(q, m);
  }
  if (l == 0){
    fs[row] = p; fd[row] = q;
    atomicMax(gmax_u, __float_as_uint(q + 64.0f));
  }
  WhT[(size_t)l*NN + row] = f2bf(Wh);
}

// ---- k_attn: wave = 16-row i-tile x split-K/8 chunk (1024 j's = 32 steps of 32).
// adj: HBM stream, 4-deep register prefetch; fd/WhT: L2-resident, 2-deep.
struct ABuf { iv4 a0, a1; };                              // 8 VGPR
struct WBuf { float4 f0, f1; short8 w0, w1, w2, w3; };    // 24 VGPR

__device__ __forceinline__ void load_adj(ABuf& b, const int* ap, int s){
  const iv4* p = (const iv4*)(ap + s*32);
  b.a0 = __builtin_nontemporal_load(p);
  b.a1 = __builtin_nontemporal_load(p + 1);
}
__device__ __forceinline__ void load_w(WBuf& b, const float* fp,
                                       const unsigned short* wp, int s){
  b.f0 = *(const float4*)(fp + s*32);
  b.f1 = *(const float4*)(fp + s*32 + 4);
  const unsigned short* wps = wp + s*32;
  b.w0 = *(const short8*)(wps);
  b.w1 = *(const short8*)(wps + 16*NN);
  b.w2 = *(const short8*)(wps + 32*NN);
  b.w3 = *(const short8*)(wps + 48*NN);
}
__device__ __forceinline__ void step(const ABuf& ab, const WBuf& wb,
    float fsr, float mrow, f32x4* acc, float& s0, float& s1){
  const int   av[8] = {ab.a0.x,ab.a0.y,ab.a0.z,ab.a0.w, ab.a1.x,ab.a1.y,ab.a1.z,ab.a1.w};
  const float fv[8] = {wb.f0.x,wb.f0.y,wb.f0.z,wb.f0.w, wb.f1.x,wb.f1.y,wb.f1.z,wb.f1.w};
  float w[8];
  #pragma unroll
  for (int j = 0; j < 8; ++j){
    float x = fsr + fv[j];
    float tt = fmaxf(x, 0.2f*x);          // leaky_relu
    float e  = __expf(tt - mrow);
    w[j] = (av[j] != 0) ? e : 0.0f;       // adj mask
  }
  s0 += (w[0]+w[2]) + (w[4]+w[6]);        // short dep chains
  s1 += (w[1]+w[3]) + (w[5]+w[7]);
  short8 af;
  __hip_bfloat162* afp = (__hip_bfloat162*)&af;
  #pragma unroll
  for (int j = 0; j < 4; ++j)
    afp[j] = __float22bfloat162_rn(make_float2(w[2*j], w[2*j+1]));  // v_cvt_pk_bf16_f32
  acc[0] = __builtin_amdgcn_mfma_f32_16x16x32_bf16(af, wb.w0, acc[0], 0,0,0);
  acc[1] = __builtin_amdgcn_mfma_f32_16x16x32_bf16(af, wb.w1, acc[1], 0,0,0);
  acc[2] = __builtin_amdgcn_mfma_f32_16x16x32_bf16(af, wb.w2, acc[2], 0,0,0);
  acc[3] = __builtin_amdgcn_mfma_f32_16x16x32_bf16(af, wb.w3, acc[3], 0,0,0);
}

// Verified layouts (m89/m120): A[m=lane&15][k=(lane>>4)*8+j],
// B[k=(lane>>4)*8+j][n=lane&15], C col=lane&15 row=(lane>>4)*4+reg.
__global__ __launch_bounds__(256, 3) void k_attn(const int* __restrict__ adj,
    const unsigned short* __restrict__ WhT, const float* __restrict__ fs,
    const float* __restrict__ fd, const unsigned* __restrict__ gmax_u,
    float* __restrict__ acc_out, float* __restrict__ s_out){
  const int l = threadIdx.x & 63;
  const int task = blockIdx.x*4 + (threadIdx.x >> 6);  // 4096 wave-tasks
  const int itile = task & 511, kchunk = task >> 9;    // 512 i-tiles x 8 splits
  const int ibase = itile*16, row = l & 15, quad = l >> 4;
  const float gmax = __uint_as_float(*gmax_u) - 64.0f;
  const float fsr  = fs[ibase + row];
  const float x0   = fsr + gmax;
  const float mrow = fmaxf(x0, 0.2f*x0);   // row-max upper bound (leaky monotone)

  const size_t koff = (size_t)kchunk*1024 + quad*8;
  const int*            ap = adj + (size_t)(ibase+row)*NN + koff;
  const float*          fp = fd + koff;
  const unsigned short* wp = WhT + (size_t)row*NN + koff;

  f32x4 acc[4];
  #pragma unroll
  for (int nb = 0; nb < 4; ++nb) acc[nb] = (f32x4){0.f,0.f,0.f,0.f};

  ABuf ab0, ab1, ab2, ab3; WBuf wb0, wb1;
  load_adj(ab0, ap, 0); load_adj(ab1, ap, 1);
  load_adj(ab2, ap, 2); load_adj(ab3, ap, 3);
  load_w(wb0, fp, wp, 0); load_w(wb1, fp, wp, 1);

  float s0 = 0.f, s1 = 0.f;
  #pragma unroll 1
  for (int s = 0; s < 28; s += 4){
    step(ab0, wb0, fsr, mrow, acc, s0, s1); load_adj(ab0, ap, s+4); load_w(wb0, fp, wp, s+2);
    step(ab1, wb1, fsr, mrow, acc, s0, s1); load_adj(ab1, ap, s+5); load_w(wb1, fp, wp, s+3);
    step(ab2, wb0, fsr, mrow, acc, s0, s1); load_adj(ab2, ap, s+6); load_w(wb0, fp, wp, s+4);
    step(ab3, wb1, fsr, mrow, acc, s0, s1); load_adj(ab3, ap, s+7); load_w(wb1, fp, wp, s+5);
  }
  step(ab0, wb0, fsr, mrow, acc, s0, s1); load_w(wb0, fp, wp, 30);
  step(ab1, wb1, fsr, mrow, acc, s0, s1); load_w(wb1, fp, wp, 31);
  step(ab2, wb0, fsr, mrow, acc, s0, s1);
  step(ab3, wb1, fsr, mrow, acc, s0, s1);

  float sacc = s0 + s1;
  sacc += __shfl_xor(sacc, 16);
  sacc += __shfl_xor(sacc, 32);
  if (l < 16) s_out[kchunk*NN + ibase + l] = sacc;
  float* op = acc_out + ((size_t)kchunk*NN + ibase)*FOUT;
  #pragma unroll
  for (int nb = 0; nb < 4; ++nb)
    #pragma unroll
    for (int r = 0; r < 4; ++r)
      op[(quad*4 + r)*FOUT + nb*16 + row] = acc[nb][r];
}

// ---- k_out: combine 8 split-K partials, normalize, ELU.
__global__ __launch_bounds__(256) void k_out(const float* __restrict__ acc,
    const float* __restrict__ s, float* __restrict__ out){
  const int idx = blockIdx.x*256 + threadIdx.x;   // 524288 total
  const int i = idx >> 6;
  float num = 0.f, den = 0.f;
  #pragma unroll
  for (int ks = 0; ks < 8; ++ks){
    num += acc[idx + (size_t)ks*(NN*FOUT)];
    den += s[i + ks*NN];
  }
  float x = num / den;
  out[idx] = (x > 0.f) ? x : (__expf(x) - 1.0f);
}

extern "C" void kernel_launch(void* const* d_in, const int* in_sizes, int n_in,
                              void* d_out, int out_size, void* d_ws, size_t ws_size,
                              hipStream_t stream){
  const float* h   = (const float*)d_in[0];
  const int*   adj = (const int*)d_in[1];
  const float* W   = (const float*)d_in[2];
  const float* a   = (const float*)d_in[3];
  char* ws = (char*)d_ws;
  // ws: [0,1M) WhT | 1M fs | 1M+32K fd | 1M+64K gmax | [2M,10M) pWh x4 |
  //     [16M,32M) acc x8 | [32M,32M+256K) s x8
  unsigned short* WhT = (unsigned short*)ws;
  float*    fs     = (float*)(ws + (1u<<20));
  float*    fd     = (float*)(ws + (1u<<20) + 32768);
  unsigned* gmax_u = (unsigned*)(ws + (1u<<20) + 65536);
  float*    pWh    = (float*)(ws + (2u<<20));
  float*    acc    = (float*)(ws + (16u<<20));
  float*    s_ws   = (float*)(ws + (32u<<20));

  (void)hipMemsetAsync(gmax_u, 0, 4, stream);
  k_prep_a<<<128, 256, 0, stream>>>(h, W, pWh);
  k_prep_b<<<2048, 256, 0, stream>>>(pWh, a, WhT, fs, fd, gmax_u);
  k_attn<<<1024, 256, 0, stream>>>(adj, WhT, fs, fd, gmax_u, acc, s_ws);
  k_out<<<2048, 256, 0, stream>>>(acc, s_ws, (float*)d_out);
}